// Round 4
// baseline (544.874 us; speedup 1.0000x reference)
//
#include <hip/hip_runtime.h>
#include <cmath>

#define CDIM 128

typedef __attribute__((ext_vector_type(8))) short bf16x8;
typedef __attribute__((ext_vector_type(4))) float f32x4;
typedef unsigned short u16;

__device__ inline unsigned pk2(float a, float b) {
    unsigned ua = __float_as_uint(a) + 0x8000u;
    unsigned ub = __float_as_uint(b) + 0x8000u;
    return (ua >> 16) | (ub & 0xffff0000u);
}
__device__ inline u16 pk1(float x) {
    return (u16)((__float_as_uint(x) + 0x8000u) >> 16);
}
__device__ inline float ubf(u16 u) { return __uint_as_float(((unsigned)u) << 16); }
__device__ inline float ulo(unsigned u) { return __uint_as_float(u << 16); }
__device__ inline float uhi(unsigned u) { return __uint_as_float(u & 0xffff0000u); }

// Merged setup #1: weight fp32->bf16 conversion (blocks [0,786)) and
// feat init-transpose (blocks [786, 786+2048)).
__global__ __launch_bounds__(256) void setup1_kernel(const float* __restrict__ w0,
                                                     const float* __restrict__ w1,
                                                     const float* __restrict__ w2,
                                                     const float* __restrict__ w3,
                                                     const float* __restrict__ b0,
                                                     const float* __restrict__ b1,
                                                     u16* __restrict__ wout,
                                                     float* __restrict__ bout,
                                                     const float* __restrict__ FL,
                                                     const float* __restrict__ FR,
                                                     u16* __restrict__ feat) {
    __shared__ float t[32][33];
    int bb = blockIdx.x;
    if (bb < 786) {                          // convert_w role
        int idx = bb * 256 + threadIdx.x;
        if (idx < 196608) {                  // float4 units
            const float* src; long off4; u16* dst;
            if (idx < 73728)       { src = w0; off4 = idx;           dst = wout; }
            else if (idx < 147456) { src = w1; off4 = idx - 73728;   dst = wout + 294912; }
            else if (idx < 172032) { src = w2; off4 = idx - 147456;  dst = wout + 589824; }
            else                   { src = w3; off4 = idx - 172032;  dst = wout + 688128; }
            float4 f = *(const float4*)(src + off4 * 4);
            *(uint2*)(dst + off4 * 4) = make_uint2(pk2(f.x, f.y), pk2(f.z, f.w));
        } else {
            int tt = idx - 196608;
            if (tt < 4608) bout[tt] = (tt < 2304) ? b0[tt] : b1[tt - 2304];
        }
        return;
    }
    // init_feat role: feat[w][n][c] (bf16) = src[c][n&63][w] — 32x32 transpose.
    int b = bb - 786;
    int cb = b & 3, wb = (b >> 2) & 3, n = b >> 4;
    const float* src = (n < 64) ? FL : FR;
    int nn = n & 63;
    int j = threadIdx.x & 31, i0 = threadIdx.x >> 5;
    #pragma unroll
    for (int p = 0; p < 4; p++) {
        int i = i0 + p * 8;
        t[i][j] = src[(cb * 32 + i) * 8192 + nn * 128 + wb * 32 + j];
    }
    __syncthreads();
    #pragma unroll
    for (int p = 0; p < 4; p++) {
        int i = i0 + p * 8;
        feat[((long)(wb * 32 + i) * 128 + n) * 128 + cb * 32 + j] = pk1(t[j][i]);
    }
}

// Merged setup #2: layer-0 self LN (blocks [0,1024)) and pp GEMM
// (blocks [1024,1216)).
__global__ __launch_bounds__(256, 4) void setup2_kernel(const u16* __restrict__ feat,
                                                        const float* __restrict__ g,
                                                        const float* __restrict__ b,
                                                        u16* __restrict__ lnB,
                                                        const float* __restrict__ Apos,
                                                        const u16* __restrict__ Wpp,
                                                        const float* __restrict__ biaspp,
                                                        u16* __restrict__ Cpp,
                                                        float scale) {
    __shared__ __align__(16) u16 sA[64 * 136];
    __shared__ __align__(16) u16 sW[64 * 136];
    int bb = blockIdx.x;
    int tid = threadIdx.x;
    if (bb < 1024) {                         // ln0 role
        int wv = tid >> 6, lane = tid & 63;
        float g0 = g[lane * 2], b0 = b[lane * 2];
        float g1 = g[lane * 2 + 1], b1 = b[lane * 2 + 1];
        #pragma unroll
        for (int rr = 0; rr < 4; rr++) {
            long m = (long)bb * 16 + wv * 4 + rr;
            unsigned u = *(const unsigned*)(feat + m * 128 + lane * 2);
            float x0 = ulo(u), x1 = uhi(u);
            float s = x0 + x1, q = x0 * x0 + x1 * x1;
            #pragma unroll
            for (int off = 1; off < 64; off <<= 1) {
                s += __shfl_xor(s, off);
                q += __shfl_xor(q, off);
            }
            float mean = s * (1.f / 128.f);
            float var = q * (1.f / 128.f) - mean * mean;
            float rs = rsqrtf(var + 1e-5f);
            float y0 = (x0 - mean) * rs * g0 + b0;
            float y1 = (x1 - mean) * rs * g1 + b1;
            *(unsigned*)(lnB + m * 128 + lane * 2) = pk2(y0, y1);
        }
        return;
    }
    // pp GEMM role -> strip-major pp: dst = ((jn>>4)*255 + m)*16 + (jn&15).
    int b2 = bb - 1024;
    int bx = b2 & 3, byy = (b2 >> 2) & 3, z = b2 >> 4;
    const int M = 255, N = 256;
    const u16* W = Wpp + (long)z * 49152;
    const float* bias = biaspp + z * 384;
    u16* C = Cpp + (long)z * 65280;
    int row0 = byy * 64, col0 = bx * 64;
    float4 zf4 = make_float4(0.f, 0.f, 0.f, 0.f);
    int kc = tid & 31;
    #pragma unroll
    for (int i = 0; i < 8; i++) {
        int r = (tid + i * 256) >> 5;
        int m = row0 + r;
        int jn = col0 + r;
        float4 fa = (m < M) ? *(const float4*)(Apos + (long)m * 128 + kc * 4) : zf4;
        uint2 uw = make_uint2(0u, 0u);
        if (jn < N) uw = *(const uint2*)(W + (long)jn * 128 + kc * 4);
        *(uint2*)&sA[r * 136 + kc * 4] = make_uint2(pk2(fa.x, fa.y), pk2(fa.z, fa.w));
        *(uint2*)&sW[r * 136 + kc * 4] = uw;
    }
    __syncthreads();

    int wv = tid >> 6, lane = tid & 63, quad = lane >> 4, col = lane & 15;
    f32x4 z4 = {0.f, 0.f, 0.f, 0.f};
    f32x4 acc0 = z4, acc1 = z4, acc2 = z4, acc3 = z4;
    #pragma unroll
    for (int kb = 0; kb < 4; kb++) {
        bf16x8 a = *(const bf16x8*)&sA[(wv * 16 + col) * 136 + kb * 32 + quad * 8];
        bf16x8 b0 = *(const bf16x8*)&sW[(0 * 16 + col) * 136 + kb * 32 + quad * 8];
        bf16x8 b1 = *(const bf16x8*)&sW[(1 * 16 + col) * 136 + kb * 32 + quad * 8];
        bf16x8 b2 = *(const bf16x8*)&sW[(2 * 16 + col) * 136 + kb * 32 + quad * 8];
        bf16x8 b3 = *(const bf16x8*)&sW[(3 * 16 + col) * 136 + kb * 32 + quad * 8];
        acc0 = __builtin_amdgcn_mfma_f32_16x16x32_bf16(a, b0, acc0, 0, 0, 0);
        acc1 = __builtin_amdgcn_mfma_f32_16x16x32_bf16(a, b1, acc1, 0, 0, 0);
        acc2 = __builtin_amdgcn_mfma_f32_16x16x32_bf16(a, b2, acc2, 0, 0, 0);
        acc3 = __builtin_amdgcn_mfma_f32_16x16x32_bf16(a, b3, acc3, 0, 0, 0);
    }
    int mrow = row0 + wv * 16 + quad * 4;
    #pragma unroll
    for (int tc = 0; tc < 4; tc++) {
        f32x4 acc = tc == 0 ? acc0 : tc == 1 ? acc1 : tc == 2 ? acc2 : acc3;
        int jn = col0 + tc * 16 + col;
        if (jn >= N) continue;
        float bs = bias[jn];
        float sc = (jn < 128) ? scale : 1.f;
        long db = ((long)(jn >> 4) * 255) * 16 + (jn & 15);
        #pragma unroll
        for (int reg = 0; reg < 4; reg++) {
            int m = mrow + reg;
            if (m >= M) continue;
            C[db + (long)m * 16] = pk1((acc[reg] + bs) * sc);
        }
    }
}

// qkv-self GEMM (layer 0 only): 128x64 tile, A = lnB.  Output strip-major.
__global__ __launch_bounds__(256, 3) void gemm_qkv128_kernel(const u16* __restrict__ A,
                                                             const u16* __restrict__ W,
                                                             const float* __restrict__ bias,
                                                             u16* __restrict__ C,
                                                             float scale) {
    __shared__ __align__(16) u16 sA[128 * 136];
    __shared__ __align__(16) u16 sW[64 * 136];
    int tid = threadIdx.x;
    int row0 = blockIdx.y * 128, col0 = blockIdx.x * 64;
    int kc = tid & 31;
    #pragma unroll
    for (int i = 0; i < 16; i++) {
        int r = (tid + i * 256) >> 5;
        *(uint2*)&sA[r * 136 + kc * 4] =
            *(const uint2*)(A + (long)(row0 + r) * 128 + kc * 4);
    }
    #pragma unroll
    for (int i = 0; i < 8; i++) {
        int r = (tid + i * 256) >> 5;
        *(uint2*)&sW[r * 136 + kc * 4] =
            *(const uint2*)(W + (long)(col0 + r) * 128 + kc * 4);
    }
    __syncthreads();

    int wv = tid >> 6, lane = tid & 63, quad = lane >> 4, col = lane & 15;
    f32x4 z4 = {0.f, 0.f, 0.f, 0.f};
    f32x4 accA0 = z4, accA1 = z4, accA2 = z4, accA3 = z4;
    f32x4 accB0 = z4, accB1 = z4, accB2 = z4, accB3 = z4;
    #pragma unroll
    for (int kb = 0; kb < 4; kb++) {
        bf16x8 a0 = *(const bf16x8*)&sA[(wv * 32 + col) * 136 + kb * 32 + quad * 8];
        bf16x8 a1 = *(const bf16x8*)&sA[(wv * 32 + 16 + col) * 136 + kb * 32 + quad * 8];
        bf16x8 b0 = *(const bf16x8*)&sW[(0 * 16 + col) * 136 + kb * 32 + quad * 8];
        bf16x8 b1 = *(const bf16x8*)&sW[(1 * 16 + col) * 136 + kb * 32 + quad * 8];
        bf16x8 b2 = *(const bf16x8*)&sW[(2 * 16 + col) * 136 + kb * 32 + quad * 8];
        bf16x8 b3 = *(const bf16x8*)&sW[(3 * 16 + col) * 136 + kb * 32 + quad * 8];
        accA0 = __builtin_amdgcn_mfma_f32_16x16x32_bf16(a0, b0, accA0, 0, 0, 0);
        accA1 = __builtin_amdgcn_mfma_f32_16x16x32_bf16(a0, b1, accA1, 0, 0, 0);
        accA2 = __builtin_amdgcn_mfma_f32_16x16x32_bf16(a0, b2, accA2, 0, 0, 0);
        accA3 = __builtin_amdgcn_mfma_f32_16x16x32_bf16(a0, b3, accA3, 0, 0, 0);
        accB0 = __builtin_amdgcn_mfma_f32_16x16x32_bf16(a1, b0, accB0, 0, 0, 0);
        accB1 = __builtin_amdgcn_mfma_f32_16x16x32_bf16(a1, b1, accB1, 0, 0, 0);
        accB2 = __builtin_amdgcn_mfma_f32_16x16x32_bf16(a1, b2, accB2, 0, 0, 0);
        accB3 = __builtin_amdgcn_mfma_f32_16x16x32_bf16(a1, b3, accB3, 0, 0, 0);
    }
    long woff = (long)blockIdx.y * 16;
    #pragma unroll
    for (int st = 0; st < 2; st++) {
        int nrow = wv * 32 + st * 16 + quad * 4;
        #pragma unroll
        for (int tc = 0; tc < 4; tc++) {
            f32x4 acc;
            if (st == 0) acc = tc == 0 ? accA0 : tc == 1 ? accA1 : tc == 2 ? accA2 : accA3;
            else         acc = tc == 0 ? accB0 : tc == 1 ? accB1 : tc == 2 ? accB2 : accB3;
            int jn = col0 + tc * 16 + col;
            float bs = bias[jn];
            float sc = (jn < 128) ? scale : 1.f;
            long db = ((long)(jn >> 4) * 128) * 2048 + woff + (jn & 15);
            #pragma unroll
            for (int reg = 0; reg < 4; reg++)
                C[db + (long)(nrow + reg) * 2048] = pk1((acc[reg] + bs) * sc);
        }
    }
}

// FUSED self out-proj + cross qkv, DIRECT-GLOBAL fragments.
// All single-use operands (vo rows, Wout, Wcr) are loaded straight from global
// as MFMA fragments: 16 B/lane covering 16 fully-consumed 64B lines per wave,
// L2-hot (weights shared by all 256 blocks).  LDS holds only the lnA tile
// (cross-lane transpose between epilogue and phase B).  ONE barrier total —
// at grid=256 (1 block/CU, 4 waves) the old 5-barrier + 35KB-restage chain
// was fully exposed.
__global__ __launch_bounds__(256, 2) void f1_out_self_cqkv_kernel(
        const u16* __restrict__ A,        // vo (self)
        const u16* __restrict__ W,        // wsel_out + i*16384
        const float* __restrict__ bias,   // self_out_b + i*128
        u16* __restrict__ feat,
        const float* __restrict__ g1, const float* __restrict__ b1,
        const float* __restrict__ g2, const float* __restrict__ b2,
        const float* __restrict__ sng, const float* __restrict__ snb,
        u16* __restrict__ lnB,
        const u16* __restrict__ Wcr,      // wcr_in + i*49152
        const float* __restrict__ biac,   // cr_in_b + i*384
        u16* __restrict__ QKV,
        float scale) {
    __shared__ __align__(16) u16 sA[64 * 136];    // lnA tile only
    int tid = threadIdx.x;
    int by = blockIdx.x;
    int row0 = by * 64;
    int right = by & 1;
    int w = by >> 1;
    int wv = tid >> 6, lane = tid & 63, quad = lane >> 4, col = lane & 15;
    int koff = quad * 8;

    // Phase A: out-proj, fragments direct from global
    f32x4 acc[8] = {};
    #pragma unroll
    for (int kb = 0; kb < 4; kb++) {
        bf16x8 a = *(const bf16x8*)(A + (long)(row0 + wv * 16 + col) * 128 + kb * 32 + koff);
        #pragma unroll
        for (int tc = 0; tc < 8; tc++) {
            bf16x8 b = *(const bf16x8*)(W + (long)(tc * 16 + col) * 128 + kb * 32 + koff);
            acc[tc] = __builtin_amdgcn_mfma_f32_16x16x32_bf16(a, b, acc[tc], 0, 0, 0);
        }
    }

    const float* gA = right ? g2 : g1;
    const float* bA = right ? b2 : b1;
    float gAv[8], bAv[8], gBv[8], bBv[8], bsv[8];
    bool doB = (sng != nullptr) && right;
    #pragma unroll
    for (int tc = 0; tc < 8; tc++) {
        int jn = tc * 16 + col;
        gAv[tc] = gA[jn]; bAv[tc] = bA[jn]; bsv[tc] = bias[jn];
        if (doB) { gBv[tc] = sng[jn]; bBv[tc] = snb[jn]; }
    }
    #pragma unroll
    for (int reg = 0; reg < 4; reg++) {
        int nloc = wv * 16 + quad * 4 + reg;
        long m = row0 + nloc;
        long rb = m * 128;
        float o[8];
        float s = 0.f, q = 0.f;
        #pragma unroll
        for (int tc = 0; tc < 8; tc++) {
            int jn = tc * 16 + col;
            float v = acc[tc][reg] + bsv[tc] + ubf(feat[rb + jn]);
            o[tc] = v; s += v; q += v * v;
        }
        #pragma unroll
        for (int off = 1; off < 16; off <<= 1) {
            s += __shfl_xor(s, off);
            q += __shfl_xor(q, off);
        }
        float mean = s * (1.f / 128.f);
        float var = q * (1.f / 128.f) - mean * mean;
        float rs = rsqrtf(var + 1e-5f);
        #pragma unroll
        for (int tc = 0; tc < 8; tc++) {
            int jn = tc * 16 + col;
            feat[rb + jn] = pk1(o[tc]);
            float ln = (o[tc] - mean) * rs;
            sA[nloc * 136 + jn] = pk1(ln * gAv[tc] + bAv[tc]);   // lnA -> LDS
            if (doB) lnB[rb + jn] = pk1(ln * gBv[tc] + bBv[tc]);
        }
    }
    __syncthreads();                   // lnA tile complete

    // Phase B: cross qkv; a-fragments hoisted to regs, B direct from global.
    bf16x8 pa[4];
    #pragma unroll
    for (int kb = 0; kb < 4; kb++)
        pa[kb] = *(const bf16x8*)&sA[(wv * 16 + col) * 136 + kb * 32 + koff];

    int passes = right ? 2 : 1;
    float sc = right ? 1.f : scale;
    int nrow = wv * 16 + quad * 4;
    for (int p = 0; p < passes; p++) {
        int wrow0 = right ? (128 + p * 128) : 0;
        f32x4 acb[8] = {};
        #pragma unroll
        for (int kb = 0; kb < 4; kb++) {
            #pragma unroll
            for (int tc = 0; tc < 8; tc++) {
                bf16x8 b = *(const bf16x8*)(Wcr + (long)(wrow0 + tc * 16 + col) * 128 + kb * 32 + koff);
                acb[tc] = __builtin_amdgcn_mfma_f32_16x16x32_bf16(pa[kb], b, acb[tc], 0, 0, 0);
            }
        }
        #pragma unroll
        for (int tc = 0; tc < 8; tc++) {
            int jn = tc * 16 + col;
            float bs = biac[wrow0 + jn];
            int strip = right ? (8 + p * 8 + (jn >> 4)) : (jn >> 4);
            long db = (long)strip * 131072 + w * 16 + (jn & 15);
            #pragma unroll
            for (int reg = 0; reg < 4; reg++)
                QKV[db + (long)(nrow + reg) * 2048] = pk1((acb[tc][reg] + bs) * sc);
        }
    }
}

// FUSED cross out-proj + NEXT layer's self-qkv, DIRECT-GLOBAL fragments.
// Left blocks: out-proj+residual+LN (fragments direct), lnB tile -> LDS,
// one barrier, 3 qkv passes (a from LDS regs, B direct).  Right blocks:
// a-fragments direct from global lnB — no LDS, no barriers at all.
__global__ __launch_bounds__(256, 2) void f2_out_cross_qkv_kernel(
        const u16* __restrict__ A,        // vo (cross)
        const u16* __restrict__ W,        // wcr_out + i*16384
        const float* __restrict__ bias,   // cr_out_b + i*128
        u16* __restrict__ feat,
        const float* __restrict__ sng,    // self_ln_g + (i+1)*128
        const float* __restrict__ snb,
        const u16* __restrict__ lnBg,     // lnB global (right rows)
        const u16* __restrict__ Wsl,      // wsel_in + (i+1)*49152
        const float* __restrict__ biasq,  // self_in_b + (i+1)*384
        u16* __restrict__ QKV,
        float scale) {
    __shared__ __align__(16) u16 sA[64 * 136];    // lnB tile (left blocks)
    int tid = threadIdx.x;
    int t = blockIdx.x;
    int right = t & 1, w = t >> 1;
    int wv = tid >> 6, lane = tid & 63, quad = lane >> 4, col = lane & 15;
    int koff = quad * 8;

    bf16x8 pa[4];
    if (!right) {
        f32x4 acc[8] = {};
        #pragma unroll
        for (int kb = 0; kb < 4; kb++) {
            bf16x8 a = *(const bf16x8*)(A + (long)(w * 64 + wv * 16 + col) * 128 + kb * 32 + koff);
            #pragma unroll
            for (int tc = 0; tc < 8; tc++) {
                bf16x8 b = *(const bf16x8*)(W + (long)(tc * 16 + col) * 128 + kb * 32 + koff);
                acc[tc] = __builtin_amdgcn_mfma_f32_16x16x32_bf16(a, b, acc[tc], 0, 0, 0);
            }
        }
        float gBv[8], bBv[8], bsv[8];
        #pragma unroll
        for (int tc = 0; tc < 8; tc++) {
            int jn = tc * 16 + col;
            gBv[tc] = sng[jn]; bBv[tc] = snb[jn]; bsv[tc] = bias[jn];
        }
        #pragma unroll
        for (int reg = 0; reg < 4; reg++) {
            int nloc = wv * 16 + quad * 4 + reg;
            long rb = ((long)w * 128 + nloc) * 128;
            float o[8];
            float s = 0.f, q = 0.f;
            #pragma unroll
            for (int tc = 0; tc < 8; tc++) {
                int jn = tc * 16 + col;
                float v = acc[tc][reg] + bsv[tc] + ubf(feat[rb + jn]);
                o[tc] = v; s += v; q += v * v;
            }
            #pragma unroll
            for (int off = 1; off < 16; off <<= 1) {
                s += __shfl_xor(s, off);
                q += __shfl_xor(q, off);
            }
            float mean = s * (1.f / 128.f);
            float var = q * (1.f / 128.f) - mean * mean;
            float rs = rsqrtf(var + 1e-5f);
            #pragma unroll
            for (int tc = 0; tc < 8; tc++) {
                int jn = tc * 16 + col;
                feat[rb + jn] = pk1(o[tc]);
                sA[nloc * 136 + jn] = pk1((o[tc] - mean) * rs * gBv[tc] + bBv[tc]);
            }
        }
        __syncthreads();               // lnB tile complete
        #pragma unroll
        for (int kb = 0; kb < 4; kb++)
            pa[kb] = *(const bf16x8*)&sA[(wv * 16 + col) * 136 + kb * 32 + koff];
    } else {
        #pragma unroll
        for (int kb = 0; kb < 4; kb++)
            pa[kb] = *(const bf16x8*)(lnBg + (long)(w * 128 + 64 + wv * 16 + col) * 128 + kb * 32 + koff);
    }

    int n0 = right ? 64 : 0;
    int nrow0 = n0 + wv * 16 + quad * 4;
    #pragma unroll
    for (int p = 0; p < 3; p++) {
        f32x4 ac[8] = {};
        #pragma unroll
        for (int kb = 0; kb < 4; kb++) {
            #pragma unroll
            for (int tc = 0; tc < 8; tc++) {
                bf16x8 b = *(const bf16x8*)(Wsl + (long)(p * 128 + tc * 16 + col) * 128 + kb * 32 + koff);
                ac[tc] = __builtin_amdgcn_mfma_f32_16x16x32_bf16(pa[kb], b, ac[tc], 0, 0, 0);
            }
        }
        #pragma unroll
        for (int tc = 0; tc < 8; tc++) {
            int jn = p * 128 + tc * 16 + col;
            float bs = biasq[jn];
            float sc = (jn < 128) ? scale : 1.f;
            long db = (long)(jn >> 4) * 262144 + w * 16 + (jn & 15);
            #pragma unroll
            for (int reg = 0; reg < 4; reg++)
                QKV[db + (long)(nrow0 + reg) * 2048] = pk1((ac[tc][reg] + bs) * sc);
        }
    }
}

// MFMA attention, 38.25 KB LDS -> 4 blocks/CU.
__global__ __launch_bounds__(512, 8) void attn_kernel(const u16* __restrict__ QKV,
                                                      const u16* __restrict__ PPL,
                                                      u16* __restrict__ VO,
                                                      float* __restrict__ RAW,
                                                      int NN, int causal) {
    __shared__ __align__(16) u16 sm[19584];
    const int SKV = 0, SA = 2176;     // K stride 16 / V^T stride 136 share SKV
    int e = blockIdx.x, n = blockIdx.y;
    int tid = threadIdx.x;
    int wv = tid >> 6, lane = tid & 63, quad = lane >> 4, col = lane & 15;

    const u16* qb = QKV + ((long)e * NN + n) * 2048;
    const u16* kb = QKV + ((long)(8 + e) * NN + n) * 2048;
    const u16* vb = QKV + ((long)(16 + e) * NN + n) * 2048;
    const u16* qr = PPL + (long)e * 4080;          // 255*16
    const u16* kr = PPL + (long)(8 + e) * 4080;

    bf16x8 zf = {0, 0, 0, 0, 0, 0, 0, 0};
    f32x4 z4 = {0.f, 0.f, 0.f, 0.f};
    bf16x8 aQ = zf, aK = zf;
    if (quad < 2) {
        aQ = *(const bf16x8*)(qb + (wv * 16 + col) * 16 + quad * 8);
        aK = *(const bf16x8*)(kb + (wv * 16 + col) * 16 + quad * 8);
    }
    {   // stage K rows, stride 16 (contiguous copy)
        int row = tid >> 2, c = tid & 3;
        *(uint2*)&sm[SKV + row * 16 + c * 4] = *(const uint2*)(kb + row * 16 + c * 4);
    }
    __syncthreads();   // B0

    // S1 = Q K^T : 8 tiles in regs
    f32x4 s1[8];
    #pragma unroll
    for (int tv = 0; tv < 8; tv++) {
        bf16x8 b = zf;
        if (quad < 2) b = *(const bf16x8*)&sm[SKV + (tv * 16 + col) * 16 + quad * 8];
        s1[tv] = __builtin_amdgcn_mfma_f32_16x16x32_bf16(aQ, b, z4, 0, 0, 0);
    }
    // S2 = Q KR^T : B direct from global (coalesced strip); tiles [7-wv, 15-wv]
    int wbq = wv * 16 + quad * 4;
    int s2lo = 7 - wv;
    #pragma unroll 3
    for (int tt = 0; tt < 9; tt++) {
        int tr = s2lo + tt;
        bf16x8 b = zf;
        if (quad < 2) b = *(const bf16x8*)(kr + (tr * 16 + col) * 16 + quad * 8);
        f32x4 d = __builtin_amdgcn_mfma_f32_16x16x32_bf16(aQ, b, z4, 0, 0, 0);
        #pragma unroll
        for (int reg = 0; reg < 4; reg++) {
            int v = tr * 16 + col - 127 + wbq + reg;
            if (v >= 0 && v < 128) sm[SA + (wbq + reg) * 136 + v] = pk1(d[reg]);
        }
    }
    __syncthreads();   // B1
    {   // stage V^T into SKV (K dead after S1)
        int row = tid >> 2, c = tid & 3;
        uint2 uv = *(const uint2*)(vb + row * 16 + c * 4);
        sm[SKV + (c * 4 + 0) * 136 + row] = (u16)(uv.x & 0xffffu);
        sm[SKV + (c * 4 + 1) * 136 + row] = (u16)(uv.x >> 16);
        sm[SKV + (c * 4 + 2) * 136 + row] = (u16)(uv.y & 0xffffu);
        sm[SKV + (c * 4 + 3) * 136 + row] = (u16)(uv.y >> 16);
    }
    // S3 = K QR^T : B direct from global; tiles [wv, wv+8]
    #pragma unroll 3
    for (int tt = 0; tt < 9; tt++) {
        int tr = wv + tt;
        bf16x8 b = zf;
        if (quad < 2) b = *(const bf16x8*)(qr + (tr * 16 + col) * 16 + quad * 8);
        f32x4 d = __builtin_amdgcn_mfma_f32_16x16x32_bf16(aK, b, z4, 0, 0, 0);
        #pragma unroll
        for (int reg = 0; reg < 4; reg++) {
            int v = wbq + reg;
            int w = 127 + v - (tr * 16 + col);
            if (w >= 0 && w < 128) {
                int addr = SA + w * 136 + v;
                sm[addr] = pk1(ubf(sm[addr]) + d[reg]);
            }
        }
    }
    __syncthreads();   // B2

    // assembly: logits = s1 + A2; exp; row sums; P written IN PLACE over A2
    float rs0 = 0.f, rs1 = 0.f, rs2 = 0.f, rs3 = 0.f;
    #pragma unroll
    for (int tv = 0; tv < 8; tv++) {
        f32x4 c = s1[tv];
        int v = tv * 16 + col;
        #pragma unroll
        for (int reg = 0; reg < 4; reg++) {
            int w = wbq + reg;
            int addr = SA + w * 136 + v;
            float a = c[reg] + ubf(sm[addr]);
            bool live = !(causal && v > w);
            float p = live ? __expf(a) : 0.f;
            if (RAW) RAW[(long)n * 16384 + w * 128 + v] = live ? a : 0.f;
            sm[addr] = pk1(p);
            if (reg == 0) rs0 += p; else if (reg == 1) rs1 += p;
            else if (reg == 2) rs2 += p; else rs3 += p;
        }
    }
    #pragma unroll
    for (int o = 1; o < 16; o <<= 1) {
        rs0 += __shfl_xor(rs0, o);
        rs1 += __shfl_xor(rs1, o);
        rs2 += __shfl_xor(rs2, o);
        rs3 += __shfl_xor(rs3, o);
    }
    __syncthreads();   // B3

    // PV: O strip = P[wv rows] . V  (P from SA, V^T from SKV)
    f32x4 o4 = z4;
    #pragma unroll
    for (int kb = 0; kb < 4; kb++) {
        bf16x8 a = *(const bf16x8*)&sm[SA + (wv * 16 + col) * 136 + kb * 32 + quad * 8];
        bf16x8 b = *(const bf16x8*)&sm[SKV + col * 136 + kb * 32 + quad * 8];
        o4 = __builtin_amdgcn_mfma_f32_16x16x32_bf16(a, b, o4, 0, 0, 0);
    }
    float iv0 = 1.f / rs0, iv1 = 1.f / rs1, iv2 = 1.f / rs2, iv3 = 1.f / rs3;
    VO[(long)((wbq + 0) * NN + n) * CDIM + e * 16 + col] = pk1(o4[0] * iv0);
    VO[(long)((wbq + 1) * NN + n) * CDIM + e * 16 + col] = pk1(o4[1] * iv1);
    VO[(long)((wbq + 2) * NN + n) * CDIM + e * 16 + col] = pk1(o4[2] * iv2);
    VO[(long)((wbq + 3) * NN + n) * CDIM + e * 16 + col] = pk1(o4[3] * iv3);
}

extern "C" void kernel_launch(void* const* d_in, const int* in_sizes, int n_in,
                              void* d_out, int out_size, void* d_ws, size_t ws_size,
                              hipStream_t stream) {
    const float* FL         = (const float*)d_in[0];
    const float* FR         = (const float*)d_in[1];
    const float* pos_enc    = (const float*)d_in[2];
    const float* self_ln_g  = (const float*)d_in[3];
    const float* self_ln_b  = (const float*)d_in[4];
    const float* self_in_w  = (const float*)d_in[5];
    const float* self_in_b  = (const float*)d_in[6];
    const float* self_out_w = (const float*)d_in[7];
    const float* self_out_b = (const float*)d_in[8];
    const float* cr_ln1_g   = (const float*)d_in[9];
    const float* cr_ln1_b   = (const float*)d_in[10];
    const float* cr_ln2_g   = (const float*)d_in[11];
    const float* cr_ln2_b   = (const float*)d_in[12];
    const float* cr_in_w    = (const float*)d_in[13];
    const float* cr_in_b    = (const float*)d_in[14];
    const float* cr_out_w   = (const float*)d_in[15];
    const float* cr_out_b   = (const float*)d_in[16];

    float* ws       = (float*)d_ws;
    u16*   feat     = (u16*)ws;                    // 16384x128 bf16
    u16*   vo       = (u16*)(ws + 1048576);
    u16*   qkvS     = (u16*)(ws + 2097152);        // strip-major qkv (24 strips)
    u16*   pp_self  = (u16*)(ws + 5242880);        // 6 x 65280 bf16 (strip-major)
    u16*   pp_cross = pp_self + 391680;
    u16*   wbf      = (u16*)(ws + 5634560);        // bf16 weights
    u16*   wsel_in  = wbf;
    u16*   wcr_in   = wbf + 294912;
    u16*   wsel_out = wbf + 589824;
    u16*   wcr_out  = wbf + 688128;
    float* bin      = ws + 6027776;                // [self_in_b | cr_in_b]
    u16*   lnB      = (u16*)(ws + 7080960);        // self-LN'ed feat
    float* out      = (float*)d_out;

    const float scale = 0.25f;                     // HD^-0.5 = 1/4

    setup1_kernel<<<2834, 256, 0, stream>>>(self_in_w, cr_in_w, self_out_w, cr_out_w,
                                            self_in_b, cr_in_b, wbf, bin,
                                            FL, FR, feat);
    setup2_kernel<<<1216, 256, 0, stream>>>(feat, self_ln_g, self_ln_b, lnB,
                                            pos_enc, wsel_in, bin, pp_self, scale);
    gemm_qkv128_kernel<<<dim3(6, 128), 256, 0, stream>>>(lnB, wsel_in,
                                                         self_in_b, qkvS, scale);

    for (int i = 0; i < 6; i++) {
        int last = (i == 5);
        // ---------------- self attention (n = 128) ----------------
        attn_kernel<<<dim3(8, 128), 512, 0, stream>>>(qkvS, pp_self + i * 65280,
                                                      vo, nullptr, 128, 0);
        // fused: self out-proj (+LN) + cross qkv projection
        f1_out_self_cqkv_kernel<<<256, 256, 0, stream>>>(vo, wsel_out + i * 16384,
                                                         self_out_b + i * 128, feat,
                                                         cr_ln1_g + i * 128, cr_ln1_b + i * 128,
                                                         cr_ln2_g + i * 128, cr_ln2_b + i * 128,
                                                         last ? nullptr : self_ln_g + (i + 1) * 128,
                                                         last ? nullptr : self_ln_b + (i + 1) * 128,
                                                         lnB,
                                                         wcr_in + i * 49152,
                                                         cr_in_b + i * 384,
                                                         qkvS, scale);

        // ---------------- cross attention (n = 64) ----------------
        attn_kernel<<<dim3(8, 64), 512, 0, stream>>>(qkvS, pp_cross + i * 65280,
                                                     vo, last ? out : nullptr,
                                                     64, last);
        if (!last) {
            // fused: cross out-proj (+LN) + next layer's self qkv
            f2_out_cross_qkv_kernel<<<256, 256, 0, stream>>>(vo, wcr_out + i * 16384,
                                                             cr_out_b + i * 128, feat,
                                                             self_ln_g + (i + 1) * 128,
                                                             self_ln_b + (i + 1) * 128,
                                                             lnB,
                                                             wsel_in + (i + 1) * 49152,
                                                             self_in_b + (i + 1) * 384,
                                                             qkvS, scale);
        }
    }
}

// Round 7
// 449.785 us; speedup vs baseline: 1.2114x; 1.2114x over previous
//
#include <hip/hip_runtime.h>
#include <cmath>

#define CDIM 128

typedef __attribute__((ext_vector_type(8))) short bf16x8;
typedef __attribute__((ext_vector_type(4))) float f32x4;
typedef unsigned short u16;

__device__ inline unsigned pk2(float a, float b) {
    unsigned ua = __float_as_uint(a) + 0x8000u;
    unsigned ub = __float_as_uint(b) + 0x8000u;
    return (ua >> 16) | (ub & 0xffff0000u);
}
__device__ inline u16 pk1(float x) {
    return (u16)((__float_as_uint(x) + 0x8000u) >> 16);
}
__device__ inline float ubf(u16 u) { return __uint_as_float(((unsigned)u) << 16); }
__device__ inline float ulo(unsigned u) { return __uint_as_float(u << 16); }
__device__ inline float uhi(unsigned u) { return __uint_as_float(u & 0xffff0000u); }

// Merged setup #1: weight fp32->bf16 conversion (blocks [0,786)) and
// feat init-transpose (blocks [786, 786+2048)).
__global__ __launch_bounds__(256) void setup1_kernel(const float* __restrict__ w0,
                                                     const float* __restrict__ w1,
                                                     const float* __restrict__ w2,
                                                     const float* __restrict__ w3,
                                                     const float* __restrict__ b0,
                                                     const float* __restrict__ b1,
                                                     u16* __restrict__ wout,
                                                     float* __restrict__ bout,
                                                     const float* __restrict__ FL,
                                                     const float* __restrict__ FR,
                                                     u16* __restrict__ feat) {
    __shared__ float t[32][33];
    int bb = blockIdx.x;
    if (bb < 786) {                          // convert_w role
        int idx = bb * 256 + threadIdx.x;
        if (idx < 196608) {                  // float4 units
            const float* src; long off4; u16* dst;
            if (idx < 73728)       { src = w0; off4 = idx;           dst = wout; }
            else if (idx < 147456) { src = w1; off4 = idx - 73728;   dst = wout + 294912; }
            else if (idx < 172032) { src = w2; off4 = idx - 147456;  dst = wout + 589824; }
            else                   { src = w3; off4 = idx - 172032;  dst = wout + 688128; }
            float4 f = *(const float4*)(src + off4 * 4);
            *(uint2*)(dst + off4 * 4) = make_uint2(pk2(f.x, f.y), pk2(f.z, f.w));
        } else {
            int tt = idx - 196608;
            if (tt < 4608) bout[tt] = (tt < 2304) ? b0[tt] : b1[tt - 2304];
        }
        return;
    }
    // init_feat role: feat[w][n][c] (bf16) = src[c][n&63][w] — 32x32 transpose.
    int b = bb - 786;
    int cb = b & 3, wb = (b >> 2) & 3, n = b >> 4;
    const float* src = (n < 64) ? FL : FR;
    int nn = n & 63;
    int j = threadIdx.x & 31, i0 = threadIdx.x >> 5;
    #pragma unroll
    for (int p = 0; p < 4; p++) {
        int i = i0 + p * 8;
        t[i][j] = src[(cb * 32 + i) * 8192 + nn * 128 + wb * 32 + j];
    }
    __syncthreads();
    #pragma unroll
    for (int p = 0; p < 4; p++) {
        int i = i0 + p * 8;
        feat[((long)(wb * 32 + i) * 128 + n) * 128 + cb * 32 + j] = pk1(t[j][i]);
    }
}

// Merged setup #2: layer-0 self LN (blocks [0,1024)) and pp GEMM
// (blocks [1024,1216)).
__global__ __launch_bounds__(256, 4) void setup2_kernel(const u16* __restrict__ feat,
                                                        const float* __restrict__ g,
                                                        const float* __restrict__ b,
                                                        u16* __restrict__ lnB,
                                                        const float* __restrict__ Apos,
                                                        const u16* __restrict__ Wpp,
                                                        const float* __restrict__ biaspp,
                                                        u16* __restrict__ Cpp,
                                                        float scale) {
    __shared__ __align__(16) u16 sA[64 * 136];
    __shared__ __align__(16) u16 sW[64 * 136];
    int bb = blockIdx.x;
    int tid = threadIdx.x;
    if (bb < 1024) {                         // ln0 role
        int wv = tid >> 6, lane = tid & 63;
        float g0 = g[lane * 2], b0 = b[lane * 2];
        float g1 = g[lane * 2 + 1], b1 = b[lane * 2 + 1];
        #pragma unroll
        for (int rr = 0; rr < 4; rr++) {
            long m = (long)bb * 16 + wv * 4 + rr;
            unsigned u = *(const unsigned*)(feat + m * 128 + lane * 2);
            float x0 = ulo(u), x1 = uhi(u);
            float s = x0 + x1, q = x0 * x0 + x1 * x1;
            #pragma unroll
            for (int off = 1; off < 64; off <<= 1) {
                s += __shfl_xor(s, off);
                q += __shfl_xor(q, off);
            }
            float mean = s * (1.f / 128.f);
            float var = q * (1.f / 128.f) - mean * mean;
            float rs = rsqrtf(var + 1e-5f);
            float y0 = (x0 - mean) * rs * g0 + b0;
            float y1 = (x1 - mean) * rs * g1 + b1;
            *(unsigned*)(lnB + m * 128 + lane * 2) = pk2(y0, y1);
        }
        return;
    }
    // pp GEMM role -> strip-major pp: dst = ((jn>>4)*255 + m)*16 + (jn&15).
    int b2 = bb - 1024;
    int bx = b2 & 3, byy = (b2 >> 2) & 3, z = b2 >> 4;
    const int M = 255, N = 256;
    const u16* W = Wpp + (long)z * 49152;
    const float* bias = biaspp + z * 384;
    u16* C = Cpp + (long)z * 65280;
    int row0 = byy * 64, col0 = bx * 64;
    float4 zf4 = make_float4(0.f, 0.f, 0.f, 0.f);
    int kc = tid & 31;
    #pragma unroll
    for (int i = 0; i < 8; i++) {
        int r = (tid + i * 256) >> 5;
        int m = row0 + r;
        int jn = col0 + r;
        float4 fa = (m < M) ? *(const float4*)(Apos + (long)m * 128 + kc * 4) : zf4;
        uint2 uw = make_uint2(0u, 0u);
        if (jn < N) uw = *(const uint2*)(W + (long)jn * 128 + kc * 4);
        *(uint2*)&sA[r * 136 + kc * 4] = make_uint2(pk2(fa.x, fa.y), pk2(fa.z, fa.w));
        *(uint2*)&sW[r * 136 + kc * 4] = uw;
    }
    __syncthreads();

    int wv = tid >> 6, lane = tid & 63, quad = lane >> 4, col = lane & 15;
    f32x4 z4 = {0.f, 0.f, 0.f, 0.f};
    f32x4 acc0 = z4, acc1 = z4, acc2 = z4, acc3 = z4;
    #pragma unroll
    for (int kb = 0; kb < 4; kb++) {
        bf16x8 a = *(const bf16x8*)&sA[(wv * 16 + col) * 136 + kb * 32 + quad * 8];
        bf16x8 b0 = *(const bf16x8*)&sW[(0 * 16 + col) * 136 + kb * 32 + quad * 8];
        bf16x8 b1 = *(const bf16x8*)&sW[(1 * 16 + col) * 136 + kb * 32 + quad * 8];
        bf16x8 b2 = *(const bf16x8*)&sW[(2 * 16 + col) * 136 + kb * 32 + quad * 8];
        bf16x8 b3 = *(const bf16x8*)&sW[(3 * 16 + col) * 136 + kb * 32 + quad * 8];
        acc0 = __builtin_amdgcn_mfma_f32_16x16x32_bf16(a, b0, acc0, 0, 0, 0);
        acc1 = __builtin_amdgcn_mfma_f32_16x16x32_bf16(a, b1, acc1, 0, 0, 0);
        acc2 = __builtin_amdgcn_mfma_f32_16x16x32_bf16(a, b2, acc2, 0, 0, 0);
        acc3 = __builtin_amdgcn_mfma_f32_16x16x32_bf16(a, b3, acc3, 0, 0, 0);
    }
    int mrow = row0 + wv * 16 + quad * 4;
    #pragma unroll
    for (int tc = 0; tc < 4; tc++) {
        f32x4 acc = tc == 0 ? acc0 : tc == 1 ? acc1 : tc == 2 ? acc2 : acc3;
        int jn = col0 + tc * 16 + col;
        if (jn >= N) continue;
        float bs = bias[jn];
        float sc = (jn < 128) ? scale : 1.f;
        long db = ((long)(jn >> 4) * 255) * 16 + (jn & 15);
        #pragma unroll
        for (int reg = 0; reg < 4; reg++) {
            int m = mrow + reg;
            if (m >= M) continue;
            C[db + (long)m * 16] = pk1((acc[reg] + bs) * sc);
        }
    }
}

// qkv-self GEMM (layer 0 only): 128x64 tile, A = lnB.  Output strip-major.
__global__ __launch_bounds__(256, 3) void gemm_qkv128_kernel(const u16* __restrict__ A,
                                                             const u16* __restrict__ W,
                                                             const float* __restrict__ bias,
                                                             u16* __restrict__ C,
                                                             float scale) {
    __shared__ __align__(16) u16 sA[128 * 136];
    __shared__ __align__(16) u16 sW[64 * 136];
    int tid = threadIdx.x;
    int row0 = blockIdx.y * 128, col0 = blockIdx.x * 64;
    int kc = tid & 31;
    #pragma unroll
    for (int i = 0; i < 16; i++) {
        int r = (tid + i * 256) >> 5;
        *(uint2*)&sA[r * 136 + kc * 4] =
            *(const uint2*)(A + (long)(row0 + r) * 128 + kc * 4);
    }
    #pragma unroll
    for (int i = 0; i < 8; i++) {
        int r = (tid + i * 256) >> 5;
        *(uint2*)&sW[r * 136 + kc * 4] =
            *(const uint2*)(W + (long)(col0 + r) * 128 + kc * 4);
    }
    __syncthreads();

    int wv = tid >> 6, lane = tid & 63, quad = lane >> 4, col = lane & 15;
    f32x4 z4 = {0.f, 0.f, 0.f, 0.f};
    f32x4 accA0 = z4, accA1 = z4, accA2 = z4, accA3 = z4;
    f32x4 accB0 = z4, accB1 = z4, accB2 = z4, accB3 = z4;
    #pragma unroll
    for (int kb = 0; kb < 4; kb++) {
        bf16x8 a0 = *(const bf16x8*)&sA[(wv * 32 + col) * 136 + kb * 32 + quad * 8];
        bf16x8 a1 = *(const bf16x8*)&sA[(wv * 32 + 16 + col) * 136 + kb * 32 + quad * 8];
        bf16x8 b0 = *(const bf16x8*)&sW[(0 * 16 + col) * 136 + kb * 32 + quad * 8];
        bf16x8 b1 = *(const bf16x8*)&sW[(1 * 16 + col) * 136 + kb * 32 + quad * 8];
        bf16x8 b2 = *(const bf16x8*)&sW[(2 * 16 + col) * 136 + kb * 32 + quad * 8];
        bf16x8 b3 = *(const bf16x8*)&sW[(3 * 16 + col) * 136 + kb * 32 + quad * 8];
        accA0 = __builtin_amdgcn_mfma_f32_16x16x32_bf16(a0, b0, accA0, 0, 0, 0);
        accA1 = __builtin_amdgcn_mfma_f32_16x16x32_bf16(a0, b1, accA1, 0, 0, 0);
        accA2 = __builtin_amdgcn_mfma_f32_16x16x32_bf16(a0, b2, accA2, 0, 0, 0);
        accA3 = __builtin_amdgcn_mfma_f32_16x16x32_bf16(a0, b3, accA3, 0, 0, 0);
        accB0 = __builtin_amdgcn_mfma_f32_16x16x32_bf16(a1, b0, accB0, 0, 0, 0);
        accB1 = __builtin_amdgcn_mfma_f32_16x16x32_bf16(a1, b1, accB1, 0, 0, 0);
        accB2 = __builtin_amdgcn_mfma_f32_16x16x32_bf16(a1, b2, accB2, 0, 0, 0);
        accB3 = __builtin_amdgcn_mfma_f32_16x16x32_bf16(a1, b3, accB3, 0, 0, 0);
    }
    long woff = (long)blockIdx.y * 16;
    #pragma unroll
    for (int st = 0; st < 2; st++) {
        int nrow = wv * 32 + st * 16 + quad * 4;
        #pragma unroll
        for (int tc = 0; tc < 4; tc++) {
            f32x4 acc;
            if (st == 0) acc = tc == 0 ? accA0 : tc == 1 ? accA1 : tc == 2 ? accA2 : accA3;
            else         acc = tc == 0 ? accB0 : tc == 1 ? accB1 : tc == 2 ? accB2 : accB3;
            int jn = col0 + tc * 16 + col;
            float bs = bias[jn];
            float sc = (jn < 128) ? scale : 1.f;
            long db = ((long)(jn >> 4) * 128) * 2048 + woff + (jn & 15);
            #pragma unroll
            for (int reg = 0; reg < 4; reg++)
                C[db + (long)(nrow + reg) * 2048] = pk1((acc[reg] + bs) * sc);
        }
    }
}

// FUSED self out-proj + cross qkv, 512 threads / 8 waves.
// Waves 0-3: phase A (identical math to r3 — bit-identical output).  Waves 4-7
// are stagers: prefetch phase-B weight passes into registers during phase A and
// dump to LDS across barriers, hiding the 32-64 KB weight staging that was
// serial at 4 waves.  Phase B runs on all 8 waves (column-split).
__global__ __launch_bounds__(512, 1) void f1_out_self_cqkv_kernel(
        const u16* __restrict__ A,        // vo (self)
        const u16* __restrict__ W,        // wsel_out + i*16384
        const float* __restrict__ bias,   // self_out_b + i*128
        u16* __restrict__ feat,
        const float* __restrict__ g1, const float* __restrict__ b1,
        const float* __restrict__ g2, const float* __restrict__ b2,
        const float* __restrict__ sng, const float* __restrict__ snb,
        u16* __restrict__ lnB,
        const u16* __restrict__ Wcr,      // wcr_in + i*49152
        const float* __restrict__ biac,   // cr_in_b + i*384
        u16* __restrict__ QKV,
        float scale) {
    __shared__ __align__(16) u16 sA[64 * 136];    // vo tile -> lnA tile
    __shared__ __align__(16) u16 sW[128 * 136];   // Wout -> pass0 -> pass1
    int tid = threadIdx.x;
    int by = blockIdx.x;
    int row0 = by * 64;
    int right = by & 1;
    int w = by >> 1;
    int wv = tid >> 6, lane = tid & 63, quad = lane >> 4, col = lane & 15;
    int koff = quad * 8;
    int t2 = tid & 255;
    int kc = t2 & 31;
    uint2 pw0[16], pw1[16];

    if (tid < 256) {                     // stage vo + Wout
        #pragma unroll
        for (int i = 0; i < 8; i++) {
            int r = (t2 + i * 256) >> 5;
            *(uint2*)&sA[r * 136 + kc * 4] = *(const uint2*)(A + (long)(row0 + r) * 128 + kc * 4);
        }
        #pragma unroll
        for (int i = 0; i < 16; i++) {
            int r = (t2 + i * 256) >> 5;
            *(uint2*)&sW[r * 136 + kc * 4] = *(const uint2*)(W + (long)r * 128 + kc * 4);
        }
    } else {                             // prefetch cross-weight passes to regs
        int w0 = right ? 128 : 0;
        #pragma unroll
        for (int i = 0; i < 16; i++) {
            int r = (t2 + i * 256) >> 5;
            pw0[i] = *(const uint2*)(Wcr + (long)(w0 + r) * 128 + kc * 4);
        }
        if (right) {
            #pragma unroll
            for (int i = 0; i < 16; i++) {
                int r = (t2 + i * 256) >> 5;
                pw1[i] = *(const uint2*)(Wcr + (long)(256 + r) * 128 + kc * 4);
            }
        }
    }
    __syncthreads();   // B1

    // Phase A (waves 0-3 only) — identical to r3.
    f32x4 acc[8] = {};
    if (tid < 256) {
        #pragma unroll
        for (int kb = 0; kb < 4; kb++) {
            bf16x8 a = *(const bf16x8*)&sA[(wv * 16 + col) * 136 + kb * 32 + koff];
            #pragma unroll
            for (int tc = 0; tc < 8; tc++) {
                bf16x8 b = *(const bf16x8*)&sW[(tc * 16 + col) * 136 + kb * 32 + koff];
                acc[tc] = __builtin_amdgcn_mfma_f32_16x16x32_bf16(a, b, acc[tc], 0, 0, 0);
            }
        }
    }
    __syncthreads();   // B2 — sA/sW reads done

    if (tid < 256) {                     // LN epilogue -> feat, lnA->sA, lnB
        const float* gA = right ? g2 : g1;
        const float* bA = right ? b2 : b1;
        float gAv[8], bAv[8], gBv[8], bBv[8], bsv[8];
        bool doB = (sng != nullptr) && right;
        #pragma unroll
        for (int tc = 0; tc < 8; tc++) {
            int jn = tc * 16 + col;
            gAv[tc] = gA[jn]; bAv[tc] = bA[jn]; bsv[tc] = bias[jn];
            if (doB) { gBv[tc] = sng[jn]; bBv[tc] = snb[jn]; }
        }
        #pragma unroll
        for (int reg = 0; reg < 4; reg++) {
            int nloc = wv * 16 + quad * 4 + reg;
            long m = row0 + nloc;
            long rb = m * 128;
            float o[8];
            float s = 0.f, q = 0.f;
            #pragma unroll
            for (int tc = 0; tc < 8; tc++) {
                int jn = tc * 16 + col;
                float v = acc[tc][reg] + bsv[tc] + ubf(feat[rb + jn]);
                o[tc] = v; s += v; q += v * v;
            }
            #pragma unroll
            for (int off = 1; off < 16; off <<= 1) {
                s += __shfl_xor(s, off);
                q += __shfl_xor(q, off);
            }
            float mean = s * (1.f / 128.f);
            float var = q * (1.f / 128.f) - mean * mean;
            float rs = rsqrtf(var + 1e-5f);
            #pragma unroll
            for (int tc = 0; tc < 8; tc++) {
                int jn = tc * 16 + col;
                feat[rb + jn] = pk1(o[tc]);
                float ln = (o[tc] - mean) * rs;
                sA[nloc * 136 + jn] = pk1(ln * gAv[tc] + bAv[tc]);
                if (doB) lnB[rb + jn] = pk1(ln * gBv[tc] + bBv[tc]);
            }
        }
    } else {                             // dump pass-0 weights into sW
        #pragma unroll
        for (int i = 0; i < 16; i++) {
            int r = (t2 + i * 256) >> 5;
            *(uint2*)&sW[r * 136 + kc * 4] = pw0[i];
        }
    }
    __syncthreads();   // B3 — lnA + pass-0 weights ready

    // Phase B on all 8 waves: wave = (rowgrp, colgrp).
    int rowgrp = wv & 3, colgrp = wv >> 2;
    bf16x8 pa[4];
    #pragma unroll
    for (int kb = 0; kb < 4; kb++)
        pa[kb] = *(const bf16x8*)&sA[(rowgrp * 16 + col) * 136 + kb * 32 + koff];
    float sc = right ? 1.f : scale;
    int nrow = rowgrp * 16 + quad * 4;
    {   // pass 0 (q for left, k for right)
        int wrow0 = right ? 128 : 0;
        f32x4 acb[4] = {};
        #pragma unroll
        for (int kb = 0; kb < 4; kb++) {
            #pragma unroll
            for (int tc = 0; tc < 4; tc++) {
                int jn = colgrp * 64 + tc * 16 + col;
                bf16x8 b = *(const bf16x8*)&sW[jn * 136 + kb * 32 + koff];
                acb[tc] = __builtin_amdgcn_mfma_f32_16x16x32_bf16(pa[kb], b, acb[tc], 0, 0, 0);
            }
        }
        #pragma unroll
        for (int tc = 0; tc < 4; tc++) {
            int jn = colgrp * 64 + tc * 16 + col;
            float bs = biac[wrow0 + jn];
            int strip = right ? (8 + (jn >> 4)) : (jn >> 4);
            long db = (long)strip * 131072 + w * 16 + (jn & 15);
            #pragma unroll
            for (int reg = 0; reg < 4; reg++)
                QKV[db + (long)(nrow + reg) * 2048] = pk1((acb[tc][reg] + bs) * sc);
        }
    }
    if (right) {       // pass 1 (v)
        __syncthreads();   // B4 — pass-0 reads done
        if (tid >= 256) {
            #pragma unroll
            for (int i = 0; i < 16; i++) {
                int r = (t2 + i * 256) >> 5;
                *(uint2*)&sW[r * 136 + kc * 4] = pw1[i];
            }
        }
        __syncthreads();   // B5
        f32x4 acb[4] = {};
        #pragma unroll
        for (int kb = 0; kb < 4; kb++) {
            #pragma unroll
            for (int tc = 0; tc < 4; tc++) {
                int jn = colgrp * 64 + tc * 16 + col;
                bf16x8 b = *(const bf16x8*)&sW[jn * 136 + kb * 32 + koff];
                acb[tc] = __builtin_amdgcn_mfma_f32_16x16x32_bf16(pa[kb], b, acb[tc], 0, 0, 0);
            }
        }
        #pragma unroll
        for (int tc = 0; tc < 4; tc++) {
            int jn = colgrp * 64 + tc * 16 + col;
            float bs = biac[256 + jn];
            int strip = 16 + (jn >> 4);
            long db = (long)strip * 131072 + w * 16 + (jn & 15);
            #pragma unroll
            for (int reg = 0; reg < 4; reg++)
                QKV[db + (long)(nrow + reg) * 2048] = pk1((acb[tc][reg] + bs) * 1.f);
        }
    }
}

// FUSED cross out-proj + NEXT layer's self-qkv, 512 threads / 8 waves.
// Left blocks: waves 0-3 phase A (identical to r3), waves 4-7 stage the three
// 128-col W_self_in passes via register relay.  Right blocks: no phase A; pa
// direct from global lnB; all waves stage pass 0 cooperatively, regs hold
// passes 1-2.
__global__ __launch_bounds__(512, 1) void f2_out_cross_qkv_kernel(
        const u16* __restrict__ A,        // vo (cross)
        const u16* __restrict__ W,        // wcr_out + i*16384
        const float* __restrict__ bias,   // cr_out_b + i*128
        u16* __restrict__ feat,
        const float* __restrict__ sng,    // self_ln_g + (i+1)*128
        const float* __restrict__ snb,
        const u16* __restrict__ lnBg,     // lnB global (right rows)
        const u16* __restrict__ Wsl,      // wsel_in + (i+1)*49152
        const float* __restrict__ biasq,  // self_in_b + (i+1)*384
        u16* __restrict__ QKV,
        float scale) {
    __shared__ __align__(16) u16 sA[64 * 136];    // vo tile -> lnB tile
    __shared__ __align__(16) u16 sW[128 * 136];
    int tid = threadIdx.x;
    int t = blockIdx.x;
    int right = t & 1, w = t >> 1;
    int wv = tid >> 6, lane = tid & 63, quad = lane >> 4, col = lane & 15;
    int koff = quad * 8;
    int t2 = tid & 255;
    int kc = t2 & 31;
    int rowgrp = wv & 3, colgrp = wv >> 2;
    bf16x8 pa[4];

    if (!right) {
        uint2 pw0[16], pw1[16];
        if (tid < 256) {                 // stage vo + Wcr_out
            #pragma unroll
            for (int i = 0; i < 8; i++) {
                int r = (t2 + i * 256) >> 5;
                *(uint2*)&sA[r * 136 + kc * 4] =
                    *(const uint2*)(A + (long)(w * 64 + r) * 128 + kc * 4);
            }
            #pragma unroll
            for (int i = 0; i < 16; i++) {
                int r = (t2 + i * 256) >> 5;
                *(uint2*)&sW[r * 136 + kc * 4] = *(const uint2*)(W + (long)r * 128 + kc * 4);
            }
        } else {                         // prefetch qkv passes 0,1 to regs
            #pragma unroll
            for (int i = 0; i < 16; i++) {
                int r = (t2 + i * 256) >> 5;
                pw0[i] = *(const uint2*)(Wsl + (long)r * 128 + kc * 4);
            }
            #pragma unroll
            for (int i = 0; i < 16; i++) {
                int r = (t2 + i * 256) >> 5;
                pw1[i] = *(const uint2*)(Wsl + (long)(128 + r) * 128 + kc * 4);
            }
        }
        __syncthreads();   // B1

        f32x4 acc[8] = {};
        if (tid < 256) {
            #pragma unroll
            for (int kb = 0; kb < 4; kb++) {
                bf16x8 a = *(const bf16x8*)&sA[(wv * 16 + col) * 136 + kb * 32 + koff];
                #pragma unroll
                for (int tc = 0; tc < 8; tc++) {
                    bf16x8 b = *(const bf16x8*)&sW[(tc * 16 + col) * 136 + kb * 32 + koff];
                    acc[tc] = __builtin_amdgcn_mfma_f32_16x16x32_bf16(a, b, acc[tc], 0, 0, 0);
                }
            }
        }
        __syncthreads();   // B2

        if (tid < 256) {                 // epilogue -> feat, lnB tile -> sA
            float gBv[8], bBv[8], bsv[8];
            #pragma unroll
            for (int tc = 0; tc < 8; tc++) {
                int jn = tc * 16 + col;
                gBv[tc] = sng[jn]; bBv[tc] = snb[jn]; bsv[tc] = bias[jn];
            }
            #pragma unroll
            for (int reg = 0; reg < 4; reg++) {
                int nloc = wv * 16 + quad * 4 + reg;
                long rb = ((long)w * 128 + nloc) * 128;
                float o[8];
                float s = 0.f, q = 0.f;
                #pragma unroll
                for (int tc = 0; tc < 8; tc++) {
                    int jn = tc * 16 + col;
                    float v = acc[tc][reg] + bsv[tc] + ubf(feat[rb + jn]);
                    o[tc] = v; s += v; q += v * v;
                }
                #pragma unroll
                for (int off = 1; off < 16; off <<= 1) {
                    s += __shfl_xor(s, off);
                    q += __shfl_xor(q, off);
                }
                float mean = s * (1.f / 128.f);
                float var = q * (1.f / 128.f) - mean * mean;
                float rs = rsqrtf(var + 1e-5f);
                #pragma unroll
                for (int tc = 0; tc < 8; tc++) {
                    int jn = tc * 16 + col;
                    feat[rb + jn] = pk1(o[tc]);
                    sA[nloc * 136 + jn] = pk1((o[tc] - mean) * rs * gBv[tc] + bBv[tc]);
                }
            }
        } else {                         // dump pass 0, prefetch pass 2
            #pragma unroll
            for (int i = 0; i < 16; i++) {
                int r = (t2 + i * 256) >> 5;
                *(uint2*)&sW[r * 136 + kc * 4] = pw0[i];
            }
            #pragma unroll
            for (int i = 0; i < 16; i++) {
                int r = (t2 + i * 256) >> 5;
                pw0[i] = *(const uint2*)(Wsl + (long)(256 + r) * 128 + kc * 4);
            }
        }
        __syncthreads();   // B3 — lnB tile + pass-0 weights ready

        #pragma unroll
        for (int kb = 0; kb < 4; kb++)
            pa[kb] = *(const bf16x8*)&sA[(rowgrp * 16 + col) * 136 + kb * 32 + koff];

        int nrow0 = rowgrp * 16 + quad * 4;
        #pragma unroll
        for (int p = 0; p < 3; p++) {
            if (p) {
                __syncthreads();         // previous pass reads done
                if (tid >= 256) {
                    #pragma unroll
                    for (int i = 0; i < 16; i++) {
                        int r = (t2 + i * 256) >> 5;
                        *(uint2*)&sW[r * 136 + kc * 4] = (p == 1) ? pw1[i] : pw0[i];
                    }
                }
                __syncthreads();
            }
            f32x4 ac[4] = {};
            #pragma unroll
            for (int kb = 0; kb < 4; kb++) {
                #pragma unroll
                for (int tc = 0; tc < 4; tc++) {
                    int jc = colgrp * 64 + tc * 16 + col;
                    bf16x8 b = *(const bf16x8*)&sW[jc * 136 + kb * 32 + koff];
                    ac[tc] = __builtin_amdgcn_mfma_f32_16x16x32_bf16(pa[kb], b, ac[tc], 0, 0, 0);
                }
            }
            #pragma unroll
            for (int tc = 0; tc < 4; tc++) {
                int jn = p * 128 + colgrp * 64 + tc * 16 + col;
                float bs = biasq[jn];
                float sc = (jn < 128) ? scale : 1.f;
                long db = (long)(jn >> 4) * 262144 + w * 16 + (jn & 15);
                #pragma unroll
                for (int reg = 0; reg < 4; reg++)
                    QKV[db + (long)(nrow0 + reg) * 2048] = pk1((ac[tc][reg] + bs) * sc);
            }
        }
    } else {
        // Right blocks: no phase A.  Cooperative pass-0 stage; regs hold 1-2.
        uint2 pwr[16];
        #pragma unroll
        for (int i = 0; i < 8; i++) {
            int r = (tid >> 5) + i * 16;
            *(uint2*)&sW[r * 136 + (tid & 31) * 4] =
                *(const uint2*)(Wsl + (long)r * 128 + (tid & 31) * 4);
        }
        int wbase = (tid < 256) ? 256 : 128;     // lower half: pass2, upper: pass1
        #pragma unroll
        for (int i = 0; i < 16; i++) {
            int r = (t2 + i * 256) >> 5;
            pwr[i] = *(const uint2*)(Wsl + (long)(wbase + r) * 128 + kc * 4);
        }
        #pragma unroll
        for (int kb = 0; kb < 4; kb++)
            pa[kb] = *(const bf16x8*)(lnBg + (long)(w * 128 + 64 + rowgrp * 16 + col) * 128 + kb * 32 + koff);
        __syncthreads();   // B1

        int nrow0 = 64 + rowgrp * 16 + quad * 4;
        #pragma unroll
        for (int p = 0; p < 3; p++) {
            if (p) {
                __syncthreads();
                bool mine = (p == 1) ? (tid >= 256) : (tid < 256);
                if (mine) {
                    #pragma unroll
                    for (int i = 0; i < 16; i++) {
                        int r = (t2 + i * 256) >> 5;
                        *(uint2*)&sW[r * 136 + kc * 4] = pwr[i];
                    }
                }
                __syncthreads();
            }
            f32x4 ac[4] = {};
            #pragma unroll
            for (int kb = 0; kb < 4; kb++) {
                #pragma unroll
                for (int tc = 0; tc < 4; tc++) {
                    int jc = colgrp * 64 + tc * 16 + col;
                    bf16x8 b = *(const bf16x8*)&sW[jc * 136 + kb * 32 + koff];
                    ac[tc] = __builtin_amdgcn_mfma_f32_16x16x32_bf16(pa[kb], b, ac[tc], 0, 0, 0);
                }
            }
            #pragma unroll
            for (int tc = 0; tc < 4; tc++) {
                int jn = p * 128 + colgrp * 64 + tc * 16 + col;
                float bs = biasq[jn];
                float sc = (jn < 128) ? scale : 1.f;
                long db = (long)(jn >> 4) * 262144 + w * 16 + (jn & 15);
                #pragma unroll
                for (int reg = 0; reg < 4; reg++)
                    QKV[db + (long)(nrow0 + reg) * 2048] = pk1((ac[tc][reg] + bs) * sc);
            }
        }
    }
}

// MFMA attention, 38.25 KB LDS -> 4 blocks/CU.
__global__ __launch_bounds__(512, 8) void attn_kernel(const u16* __restrict__ QKV,
                                                      const u16* __restrict__ PPL,
                                                      u16* __restrict__ VO,
                                                      float* __restrict__ RAW,
                                                      int NN, int causal) {
    __shared__ __align__(16) u16 sm[19584];
    const int SKV = 0, SA = 2176;     // K stride 16 / V^T stride 136 share SKV
    int e = blockIdx.x, n = blockIdx.y;
    int tid = threadIdx.x;
    int wv = tid >> 6, lane = tid & 63, quad = lane >> 4, col = lane & 15;

    const u16* qb = QKV + ((long)e * NN + n) * 2048;
    const u16* kb = QKV + ((long)(8 + e) * NN + n) * 2048;
    const u16* vb = QKV + ((long)(16 + e) * NN + n) * 2048;
    const u16* qr = PPL + (long)e * 4080;          // 255*16
    const u16* kr = PPL + (long)(8 + e) * 4080;

    bf16x8 zf = {0, 0, 0, 0, 0, 0, 0, 0};
    f32x4 z4 = {0.f, 0.f, 0.f, 0.f};
    bf16x8 aQ = zf, aK = zf;
    if (quad < 2) {
        aQ = *(const bf16x8*)(qb + (wv * 16 + col) * 16 + quad * 8);
        aK = *(const bf16x8*)(kb + (wv * 16 + col) * 16 + quad * 8);
    }
    {   // stage K rows, stride 16 (contiguous copy)
        int row = tid >> 2, c = tid & 3;
        *(uint2*)&sm[SKV + row * 16 + c * 4] = *(const uint2*)(kb + row * 16 + c * 4);
    }
    __syncthreads();   // B0

    // S1 = Q K^T : 8 tiles in regs
    f32x4 s1[8];
    #pragma unroll
    for (int tv = 0; tv < 8; tv++) {
        bf16x8 b = zf;
        if (quad < 2) b = *(const bf16x8*)&sm[SKV + (tv * 16 + col) * 16 + quad * 8];
        s1[tv] = __builtin_amdgcn_mfma_f32_16x16x32_bf16(aQ, b, z4, 0, 0, 0);
    }
    // S2 = Q KR^T : B direct from global (coalesced strip); tiles [7-wv, 15-wv]
    int wbq = wv * 16 + quad * 4;
    int s2lo = 7 - wv;
    #pragma unroll 3
    for (int tt = 0; tt < 9; tt++) {
        int tr = s2lo + tt;
        bf16x8 b = zf;
        if (quad < 2) b = *(const bf16x8*)(kr + (tr * 16 + col) * 16 + quad * 8);
        f32x4 d = __builtin_amdgcn_mfma_f32_16x16x32_bf16(aQ, b, z4, 0, 0, 0);
        #pragma unroll
        for (int reg = 0; reg < 4; reg++) {
            int v = tr * 16 + col - 127 + wbq + reg;
            if (v >= 0 && v < 128) sm[SA + (wbq + reg) * 136 + v] = pk1(d[reg]);
        }
    }
    __syncthreads();   // B1
    {   // stage V^T into SKV (K dead after S1)
        int row = tid >> 2, c = tid & 3;
        uint2 uv = *(const uint2*)(vb + row * 16 + c * 4);
        sm[SKV + (c * 4 + 0) * 136 + row] = (u16)(uv.x & 0xffffu);
        sm[SKV + (c * 4 + 1) * 136 + row] = (u16)(uv.x >> 16);
        sm[SKV + (c * 4 + 2) * 136 + row] = (u16)(uv.y & 0xffffu);
        sm[SKV + (c * 4 + 3) * 136 + row] = (u16)(uv.y >> 16);
    }
    // S3 = K QR^T : B direct from global; tiles [wv, wv+8]
    #pragma unroll 3
    for (int tt = 0; tt < 9; tt++) {
        int tr = wv + tt;
        bf16x8 b = zf;
        if (quad < 2) b = *(const bf16x8*)(qr + (tr * 16 + col) * 16 + quad * 8);
        f32x4 d = __builtin_amdgcn_mfma_f32_16x16x32_bf16(aK, b, z4, 0, 0, 0);
        #pragma unroll
        for (int reg = 0; reg < 4; reg++) {
            int v = wbq + reg;
            int w = 127 + v - (tr * 16 + col);
            if (w >= 0 && w < 128) {
                int addr = SA + w * 136 + v;
                sm[addr] = pk1(ubf(sm[addr]) + d[reg]);
            }
        }
    }
    __syncthreads();   // B2

    // assembly: logits = s1 + A2; exp; row sums; P written IN PLACE over A2
    float rs0 = 0.f, rs1 = 0.f, rs2 = 0.f, rs3 = 0.f;
    #pragma unroll
    for (int tv = 0; tv < 8; tv++) {
        f32x4 c = s1[tv];
        int v = tv * 16 + col;
        #pragma unroll
        for (int reg = 0; reg < 4; reg++) {
            int w = wbq + reg;
            int addr = SA + w * 136 + v;
            float a = c[reg] + ubf(sm[addr]);
            bool live = !(causal && v > w);
            float p = live ? __expf(a) : 0.f;
            if (RAW) RAW[(long)n * 16384 + w * 128 + v] = live ? a : 0.f;
            sm[addr] = pk1(p);
            if (reg == 0) rs0 += p; else if (reg == 1) rs1 += p;
            else if (reg == 2) rs2 += p; else rs3 += p;
        }
    }
    #pragma unroll
    for (int o = 1; o < 16; o <<= 1) {
        rs0 += __shfl_xor(rs0, o);
        rs1 += __shfl_xor(rs1, o);
        rs2 += __shfl_xor(rs2, o);
        rs3 += __shfl_xor(rs3, o);
    }
    __syncthreads();   // B3

    // PV: O strip = P[wv rows] . V  (P from SA, V^T from SKV)
    f32x4 o4 = z4;
    #pragma unroll
    for (int kb = 0; kb < 4; kb++) {
        bf16x8 a = *(const bf16x8*)&sm[SA + (wv * 16 + col) * 136 + kb * 32 + quad * 8];
        bf16x8 b = *(const bf16x8*)&sm[SKV + col * 136 + kb * 32 + quad * 8];
        o4 = __builtin_amdgcn_mfma_f32_16x16x32_bf16(a, b, o4, 0, 0, 0);
    }
    float iv0 = 1.f / rs0, iv1 = 1.f / rs1, iv2 = 1.f / rs2, iv3 = 1.f / rs3;
    VO[(long)((wbq + 0) * NN + n) * CDIM + e * 16 + col] = pk1(o4[0] * iv0);
    VO[(long)((wbq + 1) * NN + n) * CDIM + e * 16 + col] = pk1(o4[1] * iv1);
    VO[(long)((wbq + 2) * NN + n) * CDIM + e * 16 + col] = pk1(o4[2] * iv2);
    VO[(long)((wbq + 3) * NN + n) * CDIM + e * 16 + col] = pk1(o4[3] * iv3);
}

extern "C" void kernel_launch(void* const* d_in, const int* in_sizes, int n_in,
                              void* d_out, int out_size, void* d_ws, size_t ws_size,
                              hipStream_t stream) {
    const float* FL         = (const float*)d_in[0];
    const float* FR         = (const float*)d_in[1];
    const float* pos_enc    = (const float*)d_in[2];
    const float* self_ln_g  = (const float*)d_in[3];
    const float* self_ln_b  = (const float*)d_in[4];
    const float* self_in_w  = (const float*)d_in[5];
    const float* self_in_b  = (const float*)d_in[6];
    const float* self_out_w = (const float*)d_in[7];
    const float* self_out_b = (const float*)d_in[8];
    const float* cr_ln1_g   = (const float*)d_in[9];
    const float* cr_ln1_b   = (const float*)d_in[10];
    const float* cr_ln2_g   = (const float*)d_in[11];
    const float* cr_ln2_b   = (const float*)d_in[12];
    const float* cr_in_w    = (const float*)d_in[13];
    const float* cr_in_b    = (const float*)d_in[14];
    const float* cr_out_w   = (const float*)d_in[15];
    const float* cr_out_b   = (const float*)d_in[16];

    float* ws       = (float*)d_ws;
    u16*   feat     = (u16*)ws;                    // 16384x128 bf16
    u16*   vo       = (u16*)(ws + 1048576);
    u16*   qkvS     = (u16*)(ws + 2097152);        // strip-major qkv (24 strips)
    u16*   pp_self  = (u16*)(ws + 5242880);        // 6 x 65280 bf16 (strip-major)
    u16*   pp_cross = pp_self + 391680;
    u16*   wbf      = (u16*)(ws + 5634560);        // bf16 weights
    u16*   wsel_in  = wbf;
    u16*   wcr_in   = wbf + 294912;
    u16*   wsel_out = wbf + 589824;
    u16*   wcr_out  = wbf + 688128;
    float* bin      = ws + 6027776;                // [self_in_b | cr_in_b]
    u16*   lnB      = (u16*)(ws + 7080960);        // self-LN'ed feat
    float* out      = (float*)d_out;

    const float scale = 0.25f;                     // HD^-0.5 = 1/4

    setup1_kernel<<<2834, 256, 0, stream>>>(self_in_w, cr_in_w, self_out_w, cr_out_w,
                                            self_in_b, cr_in_b, wbf, bin,
                                            FL, FR, feat);
    setup2_kernel<<<1216, 256, 0, stream>>>(feat, self_ln_g, self_ln_b, lnB,
                                            pos_enc, wsel_in, bin, pp_self, scale);
    gemm_qkv128_kernel<<<dim3(6, 128), 256, 0, stream>>>(lnB, wsel_in,
                                                         self_in_b, qkvS, scale);

    for (int i = 0; i < 6; i++) {
        int last = (i == 5);
        // ---------------- self attention (n = 128) ----------------
        attn_kernel<<<dim3(8, 128), 512, 0, stream>>>(qkvS, pp_self + i * 65280,
                                                      vo, nullptr, 128, 0);
        // fused: self out-proj (+LN) + cross qkv projection (8 waves)
        f1_out_self_cqkv_kernel<<<256, 512, 0, stream>>>(vo, wsel_out + i * 16384,
                                                         self_out_b + i * 128, feat,
                                                         cr_ln1_g + i * 128, cr_ln1_b + i * 128,
                                                         cr_ln2_g + i * 128, cr_ln2_b + i * 128,
                                                         last ? nullptr : self_ln_g + (i + 1) * 128,
                                                         last ? nullptr : self_ln_b + (i + 1) * 128,
                                                         lnB,
                                                         wcr_in + i * 49152,
                                                         cr_in_b + i * 384,
                                                         qkvS, scale);

        // ---------------- cross attention (n = 64) ----------------
        attn_kernel<<<dim3(8, 64), 512, 0, stream>>>(qkvS, pp_cross + i * 65280,
                                                     vo, last ? out : nullptr,
                                                     64, last);
        if (!last) {
            // fused: cross out-proj (+LN) + next layer's self qkv (8 waves)
            f2_out_cross_qkv_kernel<<<256, 512, 0, stream>>>(vo, wcr_out + i * 16384,
                                                             cr_out_b + i * 128, feat,
                                                             self_ln_g + (i + 1) * 128,
                                                             self_ln_b + (i + 1) * 128,
                                                             lnB,
                                                             wsel_in + (i + 1) * 49152,
                                                             self_in_b + (i + 1) * 384,
                                                             qkvS, scale);
        }
    }
}